// Round 1
// baseline (615.833 us; speedup 1.0000x reference)
//
#include <hip/hip_runtime.h>
#include <math.h>

#define TLEN 7680
#define NB 256
#define CHUNK 30      // TLEN / NB
#define KMAX 386      // T//DIST + 2
#define GLEN 480      // round(T/64*4)

__device__ __forceinline__ float wsum(float v){
#pragma unroll
  for (int o = 32; o; o >>= 1) v += __shfl_xor(v, o);
  return v;
}
__device__ __forceinline__ float wmaxr(float v){
#pragma unroll
  for (int o = 32; o; o >>= 1) v = fmaxf(v, __shfl_xor(v, o));
  return v;
}
__device__ __forceinline__ float wminr(float v){
#pragma unroll
  for (int o = 32; o; o >>= 1) v = fminf(v, __shfl_xor(v, o));
  return v;
}
__device__ __forceinline__ float bsum(float v, float* sc){
  v = wsum(v);
  __syncthreads();
  if ((threadIdx.x & 63) == 0) sc[threadIdx.x >> 6] = v;
  __syncthreads();
  return sc[0] + sc[1] + sc[2] + sc[3];
}
__device__ __forceinline__ float bmax(float v, float* sc){
  v = wmaxr(v);
  __syncthreads();
  if ((threadIdx.x & 63) == 0) sc[threadIdx.x >> 6] = v;
  __syncthreads();
  return fmaxf(fmaxf(sc[0], sc[1]), fmaxf(sc[2], sc[3]));
}
__device__ __forceinline__ float bmin(float v, float* sc){
  v = wminr(v);
  __syncthreads();
  if ((threadIdx.x & 63) == 0) sc[threadIdx.x >> 6] = v;
  __syncthreads();
  return fminf(fminf(sc[0], sc[1]), fminf(sc[2], sc[3]));
}

__global__ __launch_bounds__(NB)
void bvp_feat_kernel(const float* __restrict__ x, float* __restrict__ out){
  const int tid = threadIdx.x;
  const int b = blockIdx.x;

  __shared__ __align__(16) float s_bvp[TLEN];
  __shared__ float s_rri[GLEN];
  __shared__ int   s_pk[KMAX];
  __shared__ float s_cs[256];
  __shared__ float s_sn[256];
  __shared__ int   s_cnt[NB];
  __shared__ float s_red[4];
  __shared__ float s_pw[46];
  __shared__ float s_rf[10];

  // twiddle table: cos/sin(2*pi*n/256)
  {
    float sv, cv;
    sincosf(6.283185307179586f * (float)tid * (1.0f/256.0f), &sv, &cv);
    s_cs[tid] = cv;
    s_sn[tid] = sv;
  }

  // ---- load row into LDS, fused raw moments + min/max ----
  float m1 = 0.f, m2 = 0.f, m3 = 0.f, m4 = 0.f;
  float vmn = INFINITY, vmx = -INFINITY;
  const float4* row4 = (const float4*)(x + (size_t)b * TLEN);
  float4* s4 = (float4*)s_bvp;
  for (int i = tid; i < TLEN/4; i += NB){
    float4 v = row4[i];
    s4[i] = v;
#define ACC1(a) { float _a=(a); m1+=_a; float _q=_a*_a; m2+=_q; m3+=_q*_a; m4+=_q*_q; vmn=fminf(vmn,_a); vmx=fmaxf(vmx,_a); }
    ACC1(v.x) ACC1(v.y) ACC1(v.z) ACC1(v.w)
#undef ACC1
  }
  float M1 = bsum(m1, s_red);
  float M2 = bsum(m2, s_red);
  float M3 = bsum(m3, s_red);
  float M4 = bsum(m4, s_red);
  float MN = bmin(vmn, s_red);
  float MX = bmax(vmx, s_red);
  const float invT = 1.0f / (float)TLEN;
  float mu = M1 * invT;
  float e2 = M2*invT, e3 = M3*invT, e4 = M4*invT;
  float c2 = e2 - mu*mu;
  float c3 = e3 - 3.0f*mu*e2 + 2.0f*mu*mu*mu;
  float c4 = e4 - 4.0f*mu*e3 + 6.0f*mu*mu*e2 - 3.0f*mu*mu*mu*mu;
  float sd = sqrtf(fmaxf(c2, 0.0f));
  float m2c = fmaxf(c2, 1e-30f);
  float skew = c3 / (m2c * sqrtf(m2c));
  float kurt = c4 / (m2c * m2c) - 3.0f;

  // ---- peak detection: strict local max + >= max over [t-19, t+19] ----
  const int base = tid * CHUNK;
  unsigned pmask = 0u;
  int pcnt = 0;
  {
    float prev = (base > 0) ? s_bvp[base-1] : 0.0f;
    float cur  = s_bvp[base];
    for (int o = 0; o < CHUNK; ++o){
      int t = base + o;
      float nxt = (t+1 < TLEN) ? s_bvp[t+1] : 0.0f;
      if (t >= 1 && t+1 < TLEN && cur > prev && cur > nxt){
        float v = cur;
        bool ok = true;
        int lo = t - 19; if (lo < 0) lo = 0;
        int hi = t + 19; if (hi > TLEN-1) hi = TLEN-1;
        for (int j = t-2; j >= lo; --j){ if (s_bvp[j] > v){ ok = false; break; } }
        if (ok) for (int j = t+2; j <= hi; ++j){ if (s_bvp[j] > v){ ok = false; break; } }
        if (ok){ pmask |= (1u << o); ++pcnt; }
      }
      prev = cur; cur = nxt;
    }
  }
  s_cnt[tid] = pcnt;
  __syncthreads();
  // inclusive scan (Hillis-Steele)
  for (int off = 1; off < NB; off <<= 1){
    int v = (tid >= off) ? s_cnt[tid - off] : 0;
    __syncthreads();
    s_cnt[tid] += v;
    __syncthreads();
  }
  const int total = s_cnt[NB-1];
  const int npk = total < KMAX ? total : KMAX;
  {
    int pos = s_cnt[tid] - pcnt;  // exclusive prefix
    unsigned mm = pmask;
    while (mm){
      int o = __ffs(mm) - 1;
      mm &= mm - 1u;
      if (pos < KMAX) s_pk[pos] = base + o;
      ++pos;
    }
  }
  __syncthreads();

  // ---- RR / HRV stats ----
  const int nr = npk > 1 ? npk - 1 : 0;  // valid rr count
  const int ns = npk > 2 ? npk - 2 : 0;  // valid sdf count
  const float INVFS = 1.0f/64.0f;
  float srr=0.f, shr=0.f, ssdf=0.f, ssq=0.f, c50=0.f, samp=0.f;
  float hmx = -INFINITY, hmn = INFINITY;
  for (int i = tid; i < nr; i += NB){
    float rr = (float)(s_pk[i+1]-s_pk[i]) * INVFS;
    srr += rr;
    float hr = 60.0f / fmaxf(rr, 1e-6f);
    shr += hr;
    hmx = fmaxf(hmx, hr); hmn = fminf(hmn, hr);
  }
  for (int i = tid; i < ns; i += NB){
    float r0 = (float)(s_pk[i+1]-s_pk[i]) * INVFS;
    float r1 = (float)(s_pk[i+2]-s_pk[i+1]) * INVFS;
    float d = r1 - r0;
    ssdf += d; ssq += d*d;
    if (fabsf(d) > 0.05f) c50 += 1.0f;
  }
  for (int i = tid; i < npk; i += NB) samp += s_bvp[s_pk[i]];
  float Srr = bsum(srr, s_red);
  float Shr = bsum(shr, s_red);
  float Hmx = bmax(hmx, s_red);
  float Hmn = bmin(hmn, s_red);
  float Ssdf = bsum(ssdf, s_red);
  float Ssq  = bsum(ssq, s_red);
  float C50  = bsum(c50, s_red);
  float Samp = bsum(samp, s_red);
  const float dnr = fmaxf((float)nr, 1.0f);
  const float dns = fmaxf((float)ns, 1.0f);
  const float dnp = fmaxf((float)npk, 1.0f);
  float mean_rr  = Srr / dnr;
  float mean_hr0 = Shr / dnr;
  float mean_sdf = Ssdf / dns;
  float mean_amp = Samp / dnp;
  float q_rr=0.f, q_hr=0.f, q_sdf=0.f, q_amp=0.f;
  for (int i = tid; i < nr; i += NB){
    float rr = (float)(s_pk[i+1]-s_pk[i]) * INVFS;
    float d = rr - mean_rr; q_rr += d*d;
    float hr = 60.0f / fmaxf(rr, 1e-6f);
    float dh = hr - mean_hr0; q_hr += dh*dh;
  }
  for (int i = tid; i < ns; i += NB){
    float r0 = (float)(s_pk[i+1]-s_pk[i]) * INVFS;
    float r1 = (float)(s_pk[i+2]-s_pk[i+1]) * INVFS;
    float d = (r1 - r0) - mean_sdf; q_sdf += d*d;
  }
  for (int i = tid; i < npk; i += NB){ float d = s_bvp[s_pk[i]] - mean_amp; q_amp += d*d; }
  float Qrr  = bsum(q_rr, s_red);
  float Qhr  = bsum(q_hr, s_red);
  float Qsdf = bsum(q_sdf, s_red);
  float Qamp = bsum(q_amp, s_red);

  // ---- rise/fall over first min(npk-1, 5) peaks ----
  int limit = npk - 1;
  if (limit > 5) limit = 5;
  if (limit < 0) limit = 0;
  if (tid < 5){
    float rise = 0.f, fall = 0.f;
    if (tid < limit){
      int pk = s_pk[tid];
      float best = INFINITY; int am = 0;
      for (int off = 0; off < 20; ++off){
        int bi = pk - 20 + off;
        float v = (bi >= 0) ? s_bvp[bi] : INFINITY;
        if (v < best){ best = v; am = off; }
      }
      rise = (float)(20 - am) * INVFS;
      best = INFINITY; am = 0;
      for (int off = 0; off < 20; ++off){
        int fi = pk + off;
        float v = (fi < TLEN) ? s_bvp[fi] : INFINITY;
        if (v < best){ best = v; am = off; }
      }
      fall = (float)am * INVFS;
    }
    s_rf[tid] = rise;
    s_rf[5 + tid] = fall;
  }
  __syncthreads();
  float rise_sum = s_rf[0]+s_rf[1]+s_rf[2]+s_rf[3]+s_rf[4];
  float fall_sum = s_rf[5]+s_rf[6]+s_rf[7]+s_rf[8]+s_rf[9];
  const float dlim = fmaxf((float)limit, 1.0f);

  // ---- interp to 4 Hz + Welch band powers (only when cond) ----
  float t_last = (npk >= 1) ? (float)(s_pk[npk-1]-s_pk[0]) * INVFS : 0.0f;
  const bool cond = (npk >= 3) && (t_last * 4.0f > 10.0f);  // uniform per block
  float lf = 0.f, hf = 0.f, lfhf = 0.f;
  if (cond){
    const int p0 = s_pk[0];
    for (int g = tid; g < GLEN; g += NB){
      float t = (float)g * 0.25f;
      // largest j in [0, npk-1] with t_knot[j] <= t  (t_knot[j] = (pk[j]-pk[0])/64, exact)
      int lo = 0, hi = npk - 1;
      while (lo < hi){
        int mid = (lo + hi + 1) >> 1;
        float tk = (float)(s_pk[mid]-p0) * INVFS;
        if (tk <= t) lo = mid; else hi = mid - 1;
      }
      int j = lo;
      float v;
      if (j >= npk-1){
        v = (float)(s_pk[npk-1]-s_pk[npk-2]) * INVFS;  // v_last
      } else {
        float t0 = (float)(s_pk[j]-p0) * INVFS;
        float t1 = (float)(s_pk[j+1]-p0) * INVFS;
        float v0 = (j == 0) ? (float)(s_pk[1]-s_pk[0]) * INVFS
                            : (float)(s_pk[j]-s_pk[j-1]) * INVFS;
        float v1 = (float)(s_pk[j+1]-s_pk[j]) * INVFS;
        v = v0 + (t - t0) * (v1 - v0) / (t1 - t0);
      }
      s_rri[g] = v;
    }
    __syncthreads();
    float me0 = bsum(s_rri[tid], s_red) * (1.0f/256.0f);        // seg0 = rri[0:256]
    float me1 = bsum(s_rri[128 + tid], s_red) * (1.0f/256.0f);  // seg1 = rri[128:384]
    // direct DFT at bins 3..25 for both segments: 46 (seg,bin) pairs over 4 waves
    const int w = tid >> 6, lane = tid & 63;
    for (int p = w; p < 46; p += 4){
      int k = 3 + (p >> 1);
      int so = (p & 1) * 128;
      float ms = (p & 1) ? me1 : me0;
      float re = 0.f, im = 0.f;
#pragma unroll
      for (int q = 0; q < 4; ++q){
        int n = lane + (q << 6);
        float xv = (s_rri[so + n] - ms) * (0.5f - 0.5f*s_cs[n]);  // Hann
        int ti = (k * n) & 255;
        re += xv * s_cs[ti];
        im -= xv * s_sn[ti];
      }
      re = wsum(re); im = wsum(im);
      if (lane == 0) s_pw[p] = (re*re + im*im) * (2.0f/384.0f);  // *2 (bins 1..127) * scale 1/(4*96)
    }
    __syncthreads();
    const float df = 0.015625f;
    float acc = 0.f;
    for (int k = 3; k <= 9; ++k){
      float pk2 = 0.5f*(s_pw[2*(k-3)] + s_pw[2*(k-3)+1]);  // mean over 2 segments
      acc += (k == 3 || k == 9) ? 0.5f*pk2 : pk2;          // trapezoid weights
    }
    lf = acc * df;
    acc = 0.f;
    for (int k = 10; k <= 25; ++k){
      float pk2 = 0.5f*(s_pw[2*(k-3)] + s_pw[2*(k-3)+1]);
      acc += (k == 10 || k == 25) ? 0.5f*pk2 : pk2;
    }
    hf = acc * df;
    if (hf > 0.f) lfhf = lf / fmaxf(hf, 1e-12f);
  }

  // ---- epilogue ----
  if (tid == 0){
    const bool g1 = npk >= 1, g2 = npk >= 2, g3 = npk >= 3;
    float sdnn  = g2 ? sqrtf(fmaxf(Qrr / dnr, 0.f)) : 0.f;
    float rmssd = g3 ? sqrtf(fmaxf(Ssq / dns, 0.f)) : 0.f;
    float pnn50 = g3 ? (C50 / dns * 100.0f) : 0.f;
    float sdsd  = g3 ? sqrtf(fmaxf(Qsdf / dns, 0.f)) : 0.f;
    float amp_mean = g1 ? mean_amp : 0.f;
    float amp_std  = g1 ? sqrtf(fmaxf(Qamp / dnp, 0.f)) : 0.f;
    float amp_cv = (g1 && amp_mean != 0.f) ? amp_std / amp_mean * 100.0f : 0.f;
    float rise_t = g2 ? rise_sum / dlim : 0.f;
    float fall_t = g2 ? fall_sum / dlim : 0.f;
    float mean_hr = (g2 && mean_rr > 0.f) ? 60.0f / fmaxf(mean_rr, 1e-6f) : 0.f;
    float std_hr = g2 ? sqrtf(fmaxf(Qhr / dnr, 0.f)) : 0.f;
    float hr_rng = g2 ? (Hmx - Hmn) : 0.f;
    float feats[23] = {mu, sd, skew, kurt, MN, MX, MX - MN, sdnn, rmssd, pnn50,
                       sdsd, lf, hf, lfhf, amp_mean, amp_std, amp_cv, rise_t,
                       fall_t, mean_hr, std_hr, hr_rng, (float)npk};
    float* o = out + (size_t)b * 23;
#pragma unroll
    for (int i = 0; i < 23; ++i){
      float v = feats[i];
      o[i] = (v == v && fabsf(v) != INFINITY) ? v : 0.0f;  // nan_to_num
    }
  }
}

extern "C" void kernel_launch(void* const* d_in, const int* in_sizes, int n_in,
                              void* d_out, int out_size, void* d_ws, size_t ws_size,
                              hipStream_t stream){
  const float* x = (const float*)d_in[0];
  float* out = (float*)d_out;
  const int B = in_sizes[0] / TLEN;
  bvp_feat_kernel<<<dim3(B), dim3(NB), 0, stream>>>(x, out);
}

// Round 2
// 125.009 us; speedup vs baseline: 4.9263x; 4.9263x over previous
//
#include <hip/hip_runtime.h>
#include <math.h>

#define TLEN 7680
#define NB 256
#define CHUNK 30      // TLEN / NB
#define KMAX 386      // T//DIST + 2
#define GLEN 480      // round(T/64*4)

__device__ __forceinline__ float wsum(float v){
#pragma unroll
  for (int o = 32; o; o >>= 1) v += __shfl_xor(v, o);
  return v;
}
__device__ __forceinline__ float wmaxr(float v){
#pragma unroll
  for (int o = 32; o; o >>= 1) v = fmaxf(v, __shfl_xor(v, o));
  return v;
}
__device__ __forceinline__ float wminr(float v){
#pragma unroll
  for (int o = 32; o; o >>= 1) v = fminf(v, __shfl_xor(v, o));
  return v;
}
__device__ __forceinline__ float bsum(float v, float* sc){
  v = wsum(v);
  __syncthreads();
  if ((threadIdx.x & 63) == 0) sc[threadIdx.x >> 6] = v;
  __syncthreads();
  return sc[0] + sc[1] + sc[2] + sc[3];
}

__global__ __launch_bounds__(NB)
void bvp_feat_kernel(const float* __restrict__ x, float* __restrict__ out){
  const int tid = threadIdx.x;
  const int lane = tid & 63;
  const int w = tid >> 6;
  const int b = blockIdx.x;

  __shared__ __align__(16) float s_bvp[TLEN];
  __shared__ float s_rri[GLEN];
  __shared__ int   s_pk[KMAX];
  __shared__ float s_cs[256];
  __shared__ float s_sn[256];
  __shared__ float s_red[4];
  __shared__ float s_r6[6][4];
  __shared__ float s_r8[8][4];
  __shared__ int   s_wtot[4];
  __shared__ float s_pw[46];
  __shared__ float s_rf[10];

  // twiddle table: cos/sin(2*pi*n/256)
  {
    float sv, cv;
    sincosf(6.283185307179586f * (float)tid * (1.0f/256.0f), &sv, &cv);
    s_cs[tid] = cv;
    s_sn[tid] = sv;
  }

  // ---- load row into LDS, fused raw moments + min/max ----
  float m1 = 0.f, m2 = 0.f, m3 = 0.f, m4 = 0.f;
  float vmn = INFINITY, vmx = -INFINITY;
  const float4* row4 = (const float4*)(x + (size_t)b * TLEN);
  float4* s4 = (float4*)s_bvp;
  for (int i = tid; i < TLEN/4; i += NB){
    float4 v = row4[i];
    s4[i] = v;
#define ACC1(a) { float _a=(a); m1+=_a; float _q=_a*_a; m2+=_q; m3+=_q*_a; m4+=_q*_q; vmn=fminf(vmn,_a); vmx=fmaxf(vmx,_a); }
    ACC1(v.x) ACC1(v.y) ACC1(v.z) ACC1(v.w)
#undef ACC1
  }
  // combined 6-way block reduction (1 barrier pair)
  m1 = wsum(m1); m2 = wsum(m2); m3 = wsum(m3); m4 = wsum(m4);
  vmn = wminr(vmn); vmx = wmaxr(vmx);
  if (lane == 0){
    s_r6[0][w] = m1; s_r6[1][w] = m2; s_r6[2][w] = m3;
    s_r6[3][w] = m4; s_r6[4][w] = vmn; s_r6[5][w] = vmx;
  }
  __syncthreads();   // also guarantees s_bvp fully populated
  float M1 = s_r6[0][0]+s_r6[0][1]+s_r6[0][2]+s_r6[0][3];
  float M2 = s_r6[1][0]+s_r6[1][1]+s_r6[1][2]+s_r6[1][3];
  float M3 = s_r6[2][0]+s_r6[2][1]+s_r6[2][2]+s_r6[2][3];
  float M4 = s_r6[3][0]+s_r6[3][1]+s_r6[3][2]+s_r6[3][3];
  float MN = fminf(fminf(s_r6[4][0],s_r6[4][1]), fminf(s_r6[4][2],s_r6[4][3]));
  float MX = fmaxf(fmaxf(s_r6[5][0],s_r6[5][1]), fmaxf(s_r6[5][2],s_r6[5][3]));
  const float invT = 1.0f / (float)TLEN;
  float mu = M1 * invT;
  float e2 = M2*invT, e3 = M3*invT, e4 = M4*invT;
  float c2 = e2 - mu*mu;
  float c3 = e3 - 3.0f*mu*e2 + 2.0f*mu*mu*mu;
  float c4 = e4 - 4.0f*mu*e3 + 6.0f*mu*mu*e2 - 3.0f*mu*mu*mu*mu;
  float sd = sqrtf(fmaxf(c2, 0.0f));
  float m2c = fmaxf(c2, 1e-30f);
  float skew = c3 / (m2c * sqrtf(m2c));
  float kurt = c4 / (m2c * m2c) - 3.0f;

  // ---- peak detection: branch-free van Herk sliding-window max ----
  // wmax[t] = max over [t-19, t+19] (clipped).  For chunk [base, base+29]:
  //   S1[o]  = max(bvp[A+o .. A+38])        (A = base-19)   -> suffix pass
  //   p2(o)  = max(bvp[A+39 .. A+38+o])                      -> rolling prefix
  //   wmax   = max(S1[o], p2)
  const int base = tid * CHUNK;
  const int A = base - 19;
  float S1[CHUNK];
  {
    float run = -INFINITY;
#pragma unroll
    for (int k = 38; k >= 0; --k){
      int idx = A + k;
      float v = (idx >= 0 && idx < TLEN) ? s_bvp[idx] : -INFINITY;
      run = fmaxf(run, v);
      if (k < CHUNK) S1[k] = run;
    }
  }
  unsigned pmask = 0u;
  int pcnt = 0;
  {
    float p2 = -INFINITY;
    float prev = (base > 0) ? s_bvp[base-1] : 0.0f;
    float cur  = s_bvp[base];
#pragma unroll
    for (int o = 0; o < CHUNK; ++o){
      int t = base + o;
      float nxt = (t+1 < TLEN) ? s_bvp[t+1] : 0.0f;
      if (o > 0){
        int idx = t + 19;               // = A + 38 + o, always >= 0
        float v = (idx < TLEN) ? s_bvp[idx] : -INFINITY;
        p2 = fmaxf(p2, v);
      }
      float wm = fmaxf(S1[o], p2);
      if (t >= 1 && t+1 < TLEN && cur > prev && cur > nxt && cur >= wm){
        pmask |= (1u << o); ++pcnt;
      }
      prev = cur; cur = nxt;
    }
  }

  // ---- compact peak indices: wave shuffle scan + 1 barrier ----
  int scan = pcnt;
#pragma unroll
  for (int off = 1; off < 64; off <<= 1){
    int v = __shfl_up(scan, off);
    if (lane >= off) scan += v;
  }
  if (lane == 63) s_wtot[w] = scan;
  __syncthreads();
  int wbase = 0;
#pragma unroll
  for (int j = 0; j < 4; ++j) if (j < w) wbase += s_wtot[j];
  const int total = s_wtot[0]+s_wtot[1]+s_wtot[2]+s_wtot[3];
  const int npk = total < KMAX ? total : KMAX;
  {
    int pos = wbase + scan - pcnt;  // exclusive prefix
    unsigned mm = pmask;
    while (mm){
      int o = __ffs(mm) - 1;
      mm &= mm - 1u;
      if (pos < KMAX) s_pk[pos] = base + o;
      ++pos;
    }
  }
  __syncthreads();

  // ---- RR / HRV stats ----
  const int nr = npk > 1 ? npk - 1 : 0;  // valid rr count
  const int ns = npk > 2 ? npk - 2 : 0;  // valid sdf count
  const float INVFS = 1.0f/64.0f;
  float srr=0.f, shr=0.f, ssdf=0.f, ssq=0.f, c50=0.f, samp=0.f;
  float hmx = -INFINITY, hmn = INFINITY;
  for (int i = tid; i < nr; i += NB){
    float rr = (float)(s_pk[i+1]-s_pk[i]) * INVFS;
    srr += rr;
    float hr = 60.0f / fmaxf(rr, 1e-6f);
    shr += hr;
    hmx = fmaxf(hmx, hr); hmn = fminf(hmn, hr);
  }
  for (int i = tid; i < ns; i += NB){
    float r0 = (float)(s_pk[i+1]-s_pk[i]) * INVFS;
    float r1 = (float)(s_pk[i+2]-s_pk[i+1]) * INVFS;
    float d = r1 - r0;
    ssdf += d; ssq += d*d;
    if (fabsf(d) > 0.05f) c50 += 1.0f;
  }
  for (int i = tid; i < npk; i += NB) samp += s_bvp[s_pk[i]];
  // combined 8-way reduction (1 barrier)
  srr = wsum(srr); shr = wsum(shr); ssdf = wsum(ssdf); ssq = wsum(ssq);
  c50 = wsum(c50); samp = wsum(samp); hmx = wmaxr(hmx); hmn = wminr(hmn);
  if (lane == 0){
    s_r8[0][w]=srr; s_r8[1][w]=shr; s_r8[2][w]=ssdf; s_r8[3][w]=ssq;
    s_r8[4][w]=c50; s_r8[5][w]=samp; s_r8[6][w]=hmx; s_r8[7][w]=hmn;
  }
  __syncthreads();
  float Srr  = s_r8[0][0]+s_r8[0][1]+s_r8[0][2]+s_r8[0][3];
  float Shr  = s_r8[1][0]+s_r8[1][1]+s_r8[1][2]+s_r8[1][3];
  float Ssdf = s_r8[2][0]+s_r8[2][1]+s_r8[2][2]+s_r8[2][3];
  float Ssq  = s_r8[3][0]+s_r8[3][1]+s_r8[3][2]+s_r8[3][3];
  float C50  = s_r8[4][0]+s_r8[4][1]+s_r8[4][2]+s_r8[4][3];
  float Samp = s_r8[5][0]+s_r8[5][1]+s_r8[5][2]+s_r8[5][3];
  float Hmx  = fmaxf(fmaxf(s_r8[6][0],s_r8[6][1]), fmaxf(s_r8[6][2],s_r8[6][3]));
  float Hmn  = fminf(fminf(s_r8[7][0],s_r8[7][1]), fminf(s_r8[7][2],s_r8[7][3]));
  const float dnr = fmaxf((float)nr, 1.0f);
  const float dns = fmaxf((float)ns, 1.0f);
  const float dnp = fmaxf((float)npk, 1.0f);
  float mean_rr  = Srr / dnr;
  float mean_hr0 = Shr / dnr;
  float mean_sdf = Ssdf / dns;
  float mean_amp = Samp / dnp;
  float q_rr=0.f, q_hr=0.f, q_sdf=0.f, q_amp=0.f;
  for (int i = tid; i < nr; i += NB){
    float rr = (float)(s_pk[i+1]-s_pk[i]) * INVFS;
    float d = rr - mean_rr; q_rr += d*d;
    float hr = 60.0f / fmaxf(rr, 1e-6f);
    float dh = hr - mean_hr0; q_hr += dh*dh;
  }
  for (int i = tid; i < ns; i += NB){
    float r0 = (float)(s_pk[i+1]-s_pk[i]) * INVFS;
    float r1 = (float)(s_pk[i+2]-s_pk[i+1]) * INVFS;
    float d = (r1 - r0) - mean_sdf; q_sdf += d*d;
  }
  for (int i = tid; i < npk; i += NB){ float d = s_bvp[s_pk[i]] - mean_amp; q_amp += d*d; }
  q_rr = wsum(q_rr); q_hr = wsum(q_hr); q_sdf = wsum(q_sdf); q_amp = wsum(q_amp);
  if (lane == 0){
    s_r6[0][w]=q_rr; s_r6[1][w]=q_hr; s_r6[2][w]=q_sdf; s_r6[3][w]=q_amp;
  }
  __syncthreads();
  float Qrr  = s_r6[0][0]+s_r6[0][1]+s_r6[0][2]+s_r6[0][3];
  float Qhr  = s_r6[1][0]+s_r6[1][1]+s_r6[1][2]+s_r6[1][3];
  float Qsdf = s_r6[2][0]+s_r6[2][1]+s_r6[2][2]+s_r6[2][3];
  float Qamp = s_r6[3][0]+s_r6[3][1]+s_r6[3][2]+s_r6[3][3];

  // ---- rise/fall over first min(npk-1, 5) peaks ----
  int limit = npk - 1;
  if (limit > 5) limit = 5;
  if (limit < 0) limit = 0;
  if (tid < 5){
    float rise = 0.f, fall = 0.f;
    if (tid < limit){
      int pk = s_pk[tid];
      float best = INFINITY; int am = 0;
      for (int off = 0; off < 20; ++off){
        int bi = pk - 20 + off;
        float v = (bi >= 0) ? s_bvp[bi] : INFINITY;
        if (v < best){ best = v; am = off; }
      }
      rise = (float)(20 - am) * INVFS;
      best = INFINITY; am = 0;
      for (int off = 0; off < 20; ++off){
        int fi = pk + off;
        float v = (fi < TLEN) ? s_bvp[fi] : INFINITY;
        if (v < best){ best = v; am = off; }
      }
      fall = (float)am * INVFS;
    }
    s_rf[tid] = rise;
    s_rf[5 + tid] = fall;
  }
  __syncthreads();
  float rise_sum = s_rf[0]+s_rf[1]+s_rf[2]+s_rf[3]+s_rf[4];
  float fall_sum = s_rf[5]+s_rf[6]+s_rf[7]+s_rf[8]+s_rf[9];
  const float dlim = fmaxf((float)limit, 1.0f);

  // ---- interp to 4 Hz + Welch band powers (only when cond) ----
  float t_last = (npk >= 1) ? (float)(s_pk[npk-1]-s_pk[0]) * INVFS : 0.0f;
  const bool cond = (npk >= 3) && (t_last * 4.0f > 10.0f);  // uniform per block
  float lf = 0.f, hf = 0.f, lfhf = 0.f;
  if (cond){
    const int p0 = s_pk[0];
    for (int g = tid; g < GLEN; g += NB){
      float t = (float)g * 0.25f;
      // largest j in [0, npk-1] with t_knot[j] <= t  (t_knot[j] = (pk[j]-pk[0])/64, exact)
      int lo = 0, hi = npk - 1;
      while (lo < hi){
        int mid = (lo + hi + 1) >> 1;
        float tk = (float)(s_pk[mid]-p0) * INVFS;
        if (tk <= t) lo = mid; else hi = mid - 1;
      }
      int j = lo;
      float v;
      if (j >= npk-1){
        v = (float)(s_pk[npk-1]-s_pk[npk-2]) * INVFS;  // v_last
      } else {
        float t0 = (float)(s_pk[j]-p0) * INVFS;
        float t1 = (float)(s_pk[j+1]-p0) * INVFS;
        float v0 = (j == 0) ? (float)(s_pk[1]-s_pk[0]) * INVFS
                            : (float)(s_pk[j]-s_pk[j-1]) * INVFS;
        float v1 = (float)(s_pk[j+1]-s_pk[j]) * INVFS;
        v = v0 + (t - t0) * (v1 - v0) / (t1 - t0);
      }
      s_rri[g] = v;
    }
    __syncthreads();
    float me0 = bsum(s_rri[tid], s_red) * (1.0f/256.0f);        // seg0 = rri[0:256]
    float me1 = bsum(s_rri[128 + tid], s_red) * (1.0f/256.0f);  // seg1 = rri[128:384]
    // direct DFT at bins 3..25 for both segments: 46 (seg,bin) pairs over 4 waves
    for (int p = w; p < 46; p += 4){
      int k = 3 + (p >> 1);
      int so = (p & 1) * 128;
      float ms = (p & 1) ? me1 : me0;
      float re = 0.f, im = 0.f;
#pragma unroll
      for (int q = 0; q < 4; ++q){
        int n = lane + (q << 6);
        float xv = (s_rri[so + n] - ms) * (0.5f - 0.5f*s_cs[n]);  // Hann
        int ti = (k * n) & 255;
        re += xv * s_cs[ti];
        im -= xv * s_sn[ti];
      }
      re = wsum(re); im = wsum(im);
      if (lane == 0) s_pw[p] = (re*re + im*im) * (2.0f/384.0f);  // *2 (bins 1..127) * scale 1/(4*96)
    }
    __syncthreads();
    const float df = 0.015625f;
    float acc = 0.f;
    for (int k = 3; k <= 9; ++k){
      float pk2 = 0.5f*(s_pw[2*(k-3)] + s_pw[2*(k-3)+1]);  // mean over 2 segments
      acc += (k == 3 || k == 9) ? 0.5f*pk2 : pk2;          // trapezoid weights
    }
    lf = acc * df;
    acc = 0.f;
    for (int k = 10; k <= 25; ++k){
      float pk2 = 0.5f*(s_pw[2*(k-3)] + s_pw[2*(k-3)+1]);
      acc += (k == 10 || k == 25) ? 0.5f*pk2 : pk2;
    }
    hf = acc * df;
    if (hf > 0.f) lfhf = lf / fmaxf(hf, 1e-12f);
  }

  // ---- epilogue ----
  if (tid == 0){
    const bool g1 = npk >= 1, g2 = npk >= 2, g3 = npk >= 3;
    float sdnn  = g2 ? sqrtf(fmaxf(Qrr / dnr, 0.f)) : 0.f;
    float rmssd = g3 ? sqrtf(fmaxf(Ssq / dns, 0.f)) : 0.f;
    float pnn50 = g3 ? (C50 / dns * 100.0f) : 0.f;
    float sdsd  = g3 ? sqrtf(fmaxf(Qsdf / dns, 0.f)) : 0.f;
    float amp_mean = g1 ? mean_amp : 0.f;
    float amp_std  = g1 ? sqrtf(fmaxf(Qamp / dnp, 0.f)) : 0.f;
    float amp_cv = (g1 && amp_mean != 0.f) ? amp_std / amp_mean * 100.0f : 0.f;
    float rise_t = g2 ? rise_sum / dlim : 0.f;
    float fall_t = g2 ? fall_sum / dlim : 0.f;
    float mean_hr = (g2 && mean_rr > 0.f) ? 60.0f / fmaxf(mean_rr, 1e-6f) : 0.f;
    float std_hr = g2 ? sqrtf(fmaxf(Qhr / dnr, 0.f)) : 0.f;
    float hr_rng = g2 ? (Hmx - Hmn) : 0.f;
    float feats[23] = {mu, sd, skew, kurt, MN, MX, MX - MN, sdnn, rmssd, pnn50,
                       sdsd, lf, hf, lfhf, amp_mean, amp_std, amp_cv, rise_t,
                       fall_t, mean_hr, std_hr, hr_rng, (float)npk};
    float* o = out + (size_t)b * 23;
#pragma unroll
    for (int i = 0; i < 23; ++i){
      float v = feats[i];
      o[i] = (v == v && fabsf(v) != INFINITY) ? v : 0.0f;  // nan_to_num
    }
  }
}

extern "C" void kernel_launch(void* const* d_in, const int* in_sizes, int n_in,
                              void* d_out, int out_size, void* d_ws, size_t ws_size,
                              hipStream_t stream){
  const float* x = (const float*)d_in[0];
  float* out = (float*)d_out;
  const int B = in_sizes[0] / TLEN;
  bvp_feat_kernel<<<dim3(B), dim3(NB), 0, stream>>>(x, out);
}